// Round 6
// baseline (1474.960 us; speedup 1.0000x reference)
//
#include <hip/hip_runtime.h>
#include <hip/hip_bf16.h>

#define DIM 128
#define G4 512      // 4*DIM
#define NL 4
#define VOCAB 32000
#define BB 32
#define SS 256
#define ROWS (BB*SS)   // 8192

typedef __attribute__((ext_vector_type(8))) short short8;
typedef __attribute__((ext_vector_type(4))) float f32x4;
typedef __attribute__((ext_vector_type(4))) unsigned int uint4v;

__device__ __forceinline__ float fexp_(float x){ return __builtin_amdgcn_exp2f(x * 1.44269504088896f); }
__device__ __forceinline__ float frcp_(float x){ return __builtin_amdgcn_rcpf(x); }
__device__ __forceinline__ float sigm_(float x){ return frcp_(1.f + fexp_(-x)); }
__device__ __forceinline__ float tanh_(float x){
    float ax = fabsf(x);
    float e = fexp_(-2.f * ax);
    float t = (1.f - e) * frcp_(1.f + e);
    return x < 0.f ? -t : t;
}
__device__ __forceinline__ unsigned short f2bf(float f){   // RNE round to bf16
    unsigned u = __float_as_uint(f);
    u += 0x7fffu + ((u >> 16) & 1u);
    return (unsigned short)(u >> 16);
}

#define FMA4(cv, wv, acc) acc = fmaf(cv.x, wv.x, fmaf(cv.y, wv.y, fmaf(cv.z, wv.z, fmaf(cv.w, wv.w, acc))));

// ---- per-gate 32-float weight block (8 float4, named regs) ----
#define WDECL(p) float4 p##0,p##1,p##2,p##3,p##4,p##5,p##6,p##7;
#define WLOAD(p, src) p##0=(src)[0]; p##1=(src)[1]; p##2=(src)[2]; p##3=(src)[3]; \
                      p##4=(src)[4]; p##5=(src)[5]; p##6=(src)[6]; p##7=(src)[7];
#define DOT32(p, acc) FMA4(c0,p##0,acc) FMA4(c1,p##1,acc) FMA4(c2,p##2,acc) FMA4(c3,p##3,acc) \
                      FMA4(c4,p##4,acc) FMA4(c5,p##5,acc) FMA4(c6,p##6,acc) FMA4(c7,p##7,acc)

// bf16x2 dword -> two fp32 (lo = even element, little-endian)
#define UNPK2(d, lo_, hi_) lo_ = __uint_as_float((d) << 16); hi_ = __uint_as_float((d) & 0xffff0000u);

// full-K (128) macros for k_xw (1 gate/thread, broadcast h)
#define W_DECL_ALL \
    float4 w0,w1,w2,w3,w4,w5,w6,w7,w8,w9,w10,w11,w12,w13,w14,w15, \
           w16,w17,w18,w19,w20,w21,w22,w23,w24,w25,w26,w27,w28,w29,w30,w31;
#define W_LOAD(i) w##i = wr[i];
#define W_LOAD_ALL \
    W_LOAD(0) W_LOAD(1) W_LOAD(2) W_LOAD(3) W_LOAD(4) W_LOAD(5) W_LOAD(6) W_LOAD(7) \
    W_LOAD(8) W_LOAD(9) W_LOAD(10) W_LOAD(11) W_LOAD(12) W_LOAD(13) W_LOAD(14) W_LOAD(15) \
    W_LOAD(16) W_LOAD(17) W_LOAD(18) W_LOAD(19) W_LOAD(20) W_LOAD(21) W_LOAD(22) W_LOAD(23) \
    W_LOAD(24) W_LOAD(25) W_LOAD(26) W_LOAD(27) W_LOAD(28) W_LOAD(29) W_LOAD(30) W_LOAD(31)
#define FMA1(i, acc) acc = fmaf(h4[i].x, w##i.x, fmaf(h4[i].y, w##i.y, \
                      fmaf(h4[i].z, w##i.z, fmaf(h4[i].w, w##i.w, acc))));
#define DOT128(a0,a1,a2,a3) \
    FMA1(0,a0) FMA1(1,a0) FMA1(2,a0) FMA1(3,a0) FMA1(4,a0) FMA1(5,a0) FMA1(6,a0) FMA1(7,a0) \
    FMA1(8,a1) FMA1(9,a1) FMA1(10,a1) FMA1(11,a1) FMA1(12,a1) FMA1(13,a1) FMA1(14,a1) FMA1(15,a1) \
    FMA1(16,a2) FMA1(17,a2) FMA1(18,a2) FMA1(19,a2) FMA1(20,a2) FMA1(21,a2) FMA1(22,a2) FMA1(23,a2) \
    FMA1(24,a3) FMA1(25,a3) FMA1(26,a3) FMA1(27,a3) FMA1(28,a3) FMA1(29,a3) FMA1(30,a3) FMA1(31,a3)

// ---------------- K1: embedding gather ----------------
__global__ void k_embed(const int* __restrict__ x, const float* __restrict__ emb,
                        float* __restrict__ hseq){
    int i = blockIdx.x * blockDim.x + threadIdx.x;
    int row = i >> 5;
    int d4  = i & 31;
    int tok = x[row];
    ((float4*)hseq)[i] = ((const float4*)emb)[tok * 32 + d4];
}

// ---------------- K2: xw = hseq @ Wih^T + bih + bhh (cell-major layout) --------
// Thread tid computes gate gg = (tid&3)*128 + (tid>>2); output index for gate
// q*128+i is i*4+q == tid, so stores are fully coalesced AND k_scan reads one
// float4 (i,f,g,o) per cell. Wih/xw NON-restrict: blocks weight-load remat.
__global__ __launch_bounds__(512, 2) void k_xw(const float* __restrict__ hseq,
                                               const float* Wih,
                                               const float* __restrict__ bih,
                                               const float* __restrict__ bhh,
                                               float* xw){
    __shared__ float hs[32 * DIM];
    int g = threadIdx.x;
    int r0 = blockIdx.x * 32;
    {
        const float4* src = (const float4*)(hseq + (size_t)r0 * DIM);
        float4* dst = (float4*)hs;
        for (int j = g; j < 32 * 32; j += 512) dst[j] = src[j];
    }
    int gg = ((g & 3) << 7) + (g >> 2);   // gate row this thread owns
    const float4* wr = (const float4*)(Wih + (size_t)gg * DIM);
    W_DECL_ALL
    W_LOAD_ALL
    float bias = bih[gg] + bhh[gg];
    __syncthreads();
    for (int r = 0; r < 32; ++r){
        const float4* h4 = (const float4*)(hs + r * DIM);
        float a0 = bias, a1 = 0.f, a2 = 0.f, a3 = 0.f;
        DOT128(a0, a1, a2, a3)
        xw[(size_t)(r0 + r) * G4 + g] = (a0 + a1) + (a2 + a3);
    }
}

// ---------------- K3: LSTM scan, cell-owner layout ----------------
// 32 blocks x 512 threads. tid = cell*4 + kg. Thread holds Whh rows {q*128+cell}
// chunk [kg*32, kg*32+32) (128 fp32 in named VGPRs). h transported through LDS
// as bf16 (4x b128/thread instead of 8). Butterfly shfl_xor(1,2) within the
// 4-lane group -> every lane gets all 4 gate sums -> redundant local activation
// + cell update (identical in all 4 lanes). ONE barrier per step; no act[] LDS.
// Whh/hseq NON-restrict (blocks weight remat).
__global__ __launch_bounds__(512, 2) void k_scan(const float* __restrict__ xw,
                                                 const float* Whh,
                                                 float* hseq){
    __shared__ unsigned short hs16[2][160];   // 4 chunks x (32 bf16 + 8 pad): 80B stride, 16B-aligned
    const int tid = threadIdx.x;
    const int b = blockIdx.x;
    const int ci = tid >> 2;     // cell 0..127
    const int kg = tid & 3;      // K-chunk 0..3

    WDECL(pA) WDECL(pB) WDECL(pC) WDECL(pD)
    {
        const float4* s0 = (const float4*)(Whh + ((size_t)(0 * DIM + ci)) * DIM + kg * 32);
        const float4* s1 = (const float4*)(Whh + ((size_t)(1 * DIM + ci)) * DIM + kg * 32);
        const float4* s2 = (const float4*)(Whh + ((size_t)(2 * DIM + ci)) * DIM + kg * 32);
        const float4* s3 = (const float4*)(Whh + ((size_t)(3 * DIM + ci)) * DIM + kg * 32);
        WLOAD(pA, s0) WLOAD(pB, s1) WLOAD(pC, s2) WLOAD(pD, s3)
    }
    float c = 0.f;
    if (tid < 160) hs16[0][tid] = 0;
    const float* xwb = xw + (size_t)b * SS * G4 + ci * 4;
    float* hout = hseq + (size_t)b * SS * DIM;
    float4 xr = *(const float4*)xwb;
    __syncthreads();
    int p = 0;
    for (int t = 0; t < SS; ++t){
        float4 xn = {0.f, 0.f, 0.f, 0.f};
        if (t + 1 < SS) xn = *(const float4*)(xwb + (size_t)(t + 1) * G4);   // prefetch (L2/L3)
        const uint4v* hc = (const uint4v*)(&hs16[p][kg * 40]);
        uint4v q0 = hc[0], q1 = hc[1], q2 = hc[2], q3 = hc[3];
        float4 c0, c1, c2, c3, c4, c5, c6, c7;
        UNPK2(q0.x, c0.x, c0.y) UNPK2(q0.y, c0.z, c0.w) UNPK2(q0.z, c1.x, c1.y) UNPK2(q0.w, c1.z, c1.w)
        UNPK2(q1.x, c2.x, c2.y) UNPK2(q1.y, c2.z, c2.w) UNPK2(q1.z, c3.x, c3.y) UNPK2(q1.w, c3.z, c3.w)
        UNPK2(q2.x, c4.x, c4.y) UNPK2(q2.y, c4.z, c4.w) UNPK2(q2.z, c5.x, c5.y) UNPK2(q2.w, c5.z, c5.w)
        UNPK2(q3.x, c6.x, c6.y) UNPK2(q3.y, c6.z, c6.w) UNPK2(q3.z, c7.x, c7.y) UNPK2(q3.w, c7.z, c7.w)
        float a0 = 0.f, a1 = 0.f, a2 = 0.f, a3 = 0.f;
        DOT32(pA, a0) DOT32(pB, a1) DOT32(pC, a2) DOT32(pD, a3)
        a0 += __shfl_xor(a0, 1); a0 += __shfl_xor(a0, 2);
        a1 += __shfl_xor(a1, 1); a1 += __shfl_xor(a1, 2);
        a2 += __shfl_xor(a2, 1); a2 += __shfl_xor(a2, 2);
        a3 += __shfl_xor(a3, 1); a3 += __shfl_xor(a3, 2);
        float iv = sigm_(xr.x + a0);
        float fv = sigm_(xr.y + a1);
        float gv = tanh_(xr.z + a2);
        float ov = sigm_(xr.w + a3);
        c = fv * c + iv * gv;
        float h = ov * tanh_(c);
        if (kg == 0) hs16[p ^ 1][(ci >> 5) * 40 + (ci & 31)] = f2bf(h);
        if (kg == 1) hout[(size_t)t * DIM + ci] = h;   // fp32 h for next layer / LN
        __syncthreads();
        xr = xn; p ^= 1;
    }
}

// ---------------- K4: LayerNorm -> bf16 ----------------
__global__ void k_ln(const float* __restrict__ hseq, const float* __restrict__ gamma,
                     const float* __restrict__ beta, __hip_bfloat16* __restrict__ hn){
    int wid = threadIdx.x >> 6;
    int lane = threadIdx.x & 63;
    int row = blockIdx.x * 4 + wid;
    float2 hv = ((const float2*)(hseq + (size_t)row * DIM))[lane];
    float s = hv.x + hv.y;
    float sq = fmaf(hv.x, hv.x, hv.y * hv.y);
    for (int off = 32; off; off >>= 1){ s += __shfl_xor(s, off); sq += __shfl_xor(sq, off); }
    float mu = s * (1.f / 128.f);
    float var = sq * (1.f / 128.f) - mu * mu;
    float inv = rsqrtf(var + 1e-5f);
    float2 gv = ((const float2*)gamma)[lane];
    float2 bv = ((const float2*)beta)[lane];
    __hip_bfloat162 pr;
    pr.x = __float2bfloat16((hv.x - mu) * inv * gv.x + bv.x);
    pr.y = __float2bfloat16((hv.y - mu) * inv * gv.y + bv.y);
    ((__hip_bfloat162*)hn)[(size_t)row * 64 + lane] = pr;
}

// ---------------- K5: head_W fp32 -> bf16 ----------------
__global__ void k_cvt(const float* __restrict__ w, __hip_bfloat16* __restrict__ wb){
    int i = blockIdx.x * blockDim.x + threadIdx.x;
    float4 v = ((const float4*)w)[i];
    __hip_bfloat162 p0, p1;
    p0.x = __float2bfloat16(v.x); p0.y = __float2bfloat16(v.y);
    p1.x = __float2bfloat16(v.z); p1.y = __float2bfloat16(v.w);
    ((__hip_bfloat162*)wb)[2 * i]     = p0;
    ((__hip_bfloat162*)wb)[2 * i + 1] = p1;
}

// ---------------- K6: head GEMM (bf16 MFMA) + LDS-transposed coalesced stores --
// MFMA part unchanged (verified since round 3). Epilogue stages the 128x128
// fp32 tile in LDS (float4 [128][33], padded), then stores 16 linear float4
// per thread: each wave writes 1KB contiguous rows instead of 64B fragments.
__global__ __launch_bounds__(256) void k_head(const __hip_bfloat16* __restrict__ hn,
                                              const __hip_bfloat16* __restrict__ wb,
                                              const float* __restrict__ head_b,
                                              float* __restrict__ out){
    __shared__ f32x4 tile4[128 * 33];   // 67.6 KB
    int bn = blockIdx.x;
    int bm = blockIdx.y;
    int wid = threadIdx.x >> 6;
    int lane = threadIdx.x & 63;
    int wr = wid >> 1, wc = wid & 1;
    int row0 = bm * 128 + wr * 64;
    int col0 = bn * 128 + wc * 64;
    const short* A  = (const short*)hn;   // [8192][128]
    const short* Bp = (const short*)wb;   // [32000][128]
    f32x4 zero = {0.f, 0.f, 0.f, 0.f};
    f32x4 acc[4][4];   // [mi][ni]
#pragma unroll
    for (int i = 0; i < 4; ++i)
#pragma unroll
        for (int j = 0; j < 4; ++j) acc[i][j] = zero;
    int lrow = lane & 15;
    int kgr = (lane >> 4) * 8;
#pragma unroll
    for (int ks = 0; ks < 4; ++ks){
        short8 a[4], bf[4];
#pragma unroll
        for (int mi = 0; mi < 4; ++mi)
            a[mi] = *(const short8*)(A + (size_t)(row0 + mi * 16 + lrow) * DIM + ks * 32 + kgr);
#pragma unroll
        for (int ni = 0; ni < 4; ++ni)
            bf[ni] = *(const short8*)(Bp + (size_t)(col0 + ni * 16 + lrow) * DIM + ks * 32 + kgr);
#pragma unroll
        for (int mi = 0; mi < 4; ++mi)
#pragma unroll
            for (int ni = 0; ni < 4; ++ni)
                acc[mi][ni] = __builtin_amdgcn_mfma_f32_16x16x32_bf16(bf[ni], a[mi], acc[mi][ni], 0, 0, 0);
    }
    int csub = (lane >> 4) * 4;
#pragma unroll
    for (int ni = 0; ni < 4; ++ni){
        int lc = wc * 64 + ni * 16 + csub;              // local col 0..127 (mult of 4)
        float4 b4 = ((const float4*)head_b)[(bn * 128 + lc) >> 2];
#pragma unroll
        for (int mi = 0; mi < 4; ++mi){
            int lr = wr * 64 + mi * 16 + lrow;          // local row 0..127
            f32x4 v;
            v[0] = acc[mi][ni][0] + b4.x;
            v[1] = acc[mi][ni][1] + b4.y;
            v[2] = acc[mi][ni][2] + b4.z;
            v[3] = acc[mi][ni][3] + b4.w;
            tile4[lr * 33 + (lc >> 2)] = v;
        }
    }
    __syncthreads();
    const size_t gbase = (size_t)(bm * 128) * VOCAB + (size_t)bn * 128;
#pragma unroll
    for (int k = 0; k < 16; ++k){
        int f = k * 256 + threadIdx.x;     // flat float4 index 0..4095
        int r = f >> 5, c4 = f & 31;
        f32x4 v = tile4[r * 33 + c4];
        *(f32x4*)(out + gbase + (size_t)r * VOCAB + c4 * 4) = v;
    }
}

extern "C" void kernel_launch(void* const* d_in, const int* in_sizes, int n_in,
                              void* d_out, int out_size, void* d_ws, size_t ws_size,
                              hipStream_t stream){
    const int*   x     = (const int*)  d_in[0];
    const float* emb   = (const float*)d_in[1];
    const float* Wih   = (const float*)d_in[2];
    const float* Whh   = (const float*)d_in[3];
    const float* bih   = (const float*)d_in[4];
    const float* bhh   = (const float*)d_in[5];
    const float* gamma = (const float*)d_in[6];
    const float* beta  = (const float*)d_in[7];
    const float* headW = (const float*)d_in[8];
    const float* headb = (const float*)d_in[9];
    float* out = (float*)d_out;

    char* ws = (char*)d_ws;
    float* xw   = (float*)ws;                                  // 16 MB [8192][512] (cell-major)
    float* hseq = (float*)(ws + (16u << 20));                  // 4 MB  [8192][128]
    __hip_bfloat16* hn = (__hip_bfloat16*)(ws + (20u << 20));  // 2 MB
    __hip_bfloat16* wb = (__hip_bfloat16*)(ws + (22u << 20));  // 8 MB

    k_embed<<<1024, 256, 0, stream>>>(x, emb, hseq);
    k_cvt  <<<4000, 256, 0, stream>>>(headW, wb);
    for (int l = 0; l < NL; ++l){
        k_xw  <<<256, 512, 0, stream>>>(hseq, Wih + (size_t)l * G4 * DIM,
                                        bih + l * G4, bhh + l * G4, xw);
        k_scan<<<32, 512, 0, stream>>>(xw, Whh + (size_t)l * G4 * DIM, hseq);
    }
    k_ln   <<<2048, 256, 0, stream>>>(hseq, gamma, beta, hn);
    k_head <<<dim3(250, 64), 256, 0, stream>>>(hn, wb, headb, out);
}

// Round 7
// 1398.643 us; speedup vs baseline: 1.0546x; 1.0546x over previous
//
#include <hip/hip_runtime.h>
#include <hip/hip_bf16.h>

#define DIM 128
#define G4 512      // 4*DIM
#define NL 4
#define VOCAB 32000
#define BB 32
#define SS 256
#define ROWS (BB*SS)   // 8192

typedef __attribute__((ext_vector_type(8))) short short8;
typedef __attribute__((ext_vector_type(4))) float f32x4;
typedef __attribute__((ext_vector_type(4))) unsigned int uint4v;
typedef __attribute__((ext_vector_type(2))) _Float16 h2;

__device__ __forceinline__ float fexp_(float x){ return __builtin_amdgcn_exp2f(x * 1.44269504088896f); }
__device__ __forceinline__ float frcp_(float x){ return __builtin_amdgcn_rcpf(x); }
__device__ __forceinline__ float sigm_(float x){ return frcp_(1.f + fexp_(-x)); }
__device__ __forceinline__ float tanh_(float x){
    float ax = fabsf(x);
    float e = fexp_(-2.f * ax);
    float t = (1.f - e) * frcp_(1.f + e);
    return x < 0.f ? -t : t;
}
__device__ __forceinline__ h2 mkh(float a, float b){ h2 r; r.x = (_Float16)a; r.y = (_Float16)b; return r; }

#if __has_builtin(__builtin_amdgcn_fdot2)
#define FDOT2(w, d, acc) acc = __builtin_amdgcn_fdot2(w, d, acc, false);
#else
#define FDOT2(w, d, acc) acc = fmaf((float)(w).x, (float)(d).x, fmaf((float)(w).y, (float)(d).y, acc));
#endif
#define B2H(u) __builtin_bit_cast(h2, (unsigned)(u))

// ---- per-gate 32-elem f16 weight block: 16 named half2 regs ----
#define WDECLH(p) h2 p##0,p##1,p##2,p##3,p##4,p##5,p##6,p##7, \
                     p##8,p##9,p##10,p##11,p##12,p##13,p##14,p##15;
#define WCVTH(p, src) { float4 t_; \
    t_=(src)[0]; p##0 =mkh(t_.x,t_.y); p##1 =mkh(t_.z,t_.w); \
    t_=(src)[1]; p##2 =mkh(t_.x,t_.y); p##3 =mkh(t_.z,t_.w); \
    t_=(src)[2]; p##4 =mkh(t_.x,t_.y); p##5 =mkh(t_.z,t_.w); \
    t_=(src)[3]; p##6 =mkh(t_.x,t_.y); p##7 =mkh(t_.z,t_.w); \
    t_=(src)[4]; p##8 =mkh(t_.x,t_.y); p##9 =mkh(t_.z,t_.w); \
    t_=(src)[5]; p##10=mkh(t_.x,t_.y); p##11=mkh(t_.z,t_.w); \
    t_=(src)[6]; p##12=mkh(t_.x,t_.y); p##13=mkh(t_.z,t_.w); \
    t_=(src)[7]; p##14=mkh(t_.x,t_.y); p##15=mkh(t_.z,t_.w); }
#define DOTH(p, acc) \
    FDOT2(p##0,d0,acc)  FDOT2(p##1,d1,acc)  FDOT2(p##2,d2,acc)  FDOT2(p##3,d3,acc) \
    FDOT2(p##4,d4,acc)  FDOT2(p##5,d5,acc)  FDOT2(p##6,d6,acc)  FDOT2(p##7,d7,acc) \
    FDOT2(p##8,d8,acc)  FDOT2(p##9,d9,acc)  FDOT2(p##10,d10,acc) FDOT2(p##11,d11,acc) \
    FDOT2(p##12,d12,acc) FDOT2(p##13,d13,acc) FDOT2(p##14,d14,acc) FDOT2(p##15,d15,acc)

// full-K (128) fp32 macros for k_xw (1 gate/thread, broadcast h)
#define W_DECL_ALL \
    float4 w0,w1,w2,w3,w4,w5,w6,w7,w8,w9,w10,w11,w12,w13,w14,w15, \
           w16,w17,w18,w19,w20,w21,w22,w23,w24,w25,w26,w27,w28,w29,w30,w31;
#define W_LOAD(i) w##i = wr[i];
#define W_LOAD_ALL \
    W_LOAD(0) W_LOAD(1) W_LOAD(2) W_LOAD(3) W_LOAD(4) W_LOAD(5) W_LOAD(6) W_LOAD(7) \
    W_LOAD(8) W_LOAD(9) W_LOAD(10) W_LOAD(11) W_LOAD(12) W_LOAD(13) W_LOAD(14) W_LOAD(15) \
    W_LOAD(16) W_LOAD(17) W_LOAD(18) W_LOAD(19) W_LOAD(20) W_LOAD(21) W_LOAD(22) W_LOAD(23) \
    W_LOAD(24) W_LOAD(25) W_LOAD(26) W_LOAD(27) W_LOAD(28) W_LOAD(29) W_LOAD(30) W_LOAD(31)
#define FMA1(i, acc) acc = fmaf(h4[i].x, w##i.x, fmaf(h4[i].y, w##i.y, \
                      fmaf(h4[i].z, w##i.z, fmaf(h4[i].w, w##i.w, acc))));
#define DOT128(a0,a1,a2,a3) \
    FMA1(0,a0) FMA1(1,a0) FMA1(2,a0) FMA1(3,a0) FMA1(4,a0) FMA1(5,a0) FMA1(6,a0) FMA1(7,a0) \
    FMA1(8,a1) FMA1(9,a1) FMA1(10,a1) FMA1(11,a1) FMA1(12,a1) FMA1(13,a1) FMA1(14,a1) FMA1(15,a1) \
    FMA1(16,a2) FMA1(17,a2) FMA1(18,a2) FMA1(19,a2) FMA1(20,a2) FMA1(21,a2) FMA1(22,a2) FMA1(23,a2) \
    FMA1(24,a3) FMA1(25,a3) FMA1(26,a3) FMA1(27,a3) FMA1(28,a3) FMA1(29,a3) FMA1(30,a3) FMA1(31,a3)

// ---------------- K1: embedding gather ----------------
__global__ void k_embed(const int* __restrict__ x, const float* __restrict__ emb,
                        float* __restrict__ hseq){
    int i = blockIdx.x * blockDim.x + threadIdx.x;
    int row = i >> 5;
    int d4  = i & 31;
    int tok = x[row];
    ((float4*)hseq)[i] = ((const float4*)emb)[tok * 32 + d4];
}

// ---------------- K2: xw = hseq @ Wih^T + bih + bhh (cell-major layout) --------
// Thread tid owns gate gg = (tid&3)*128 + (tid>>2); store index == tid, so
// stores coalesce AND k_scan reads one float4 (i,f,g,o) per cell.
// Wih/xw NON-restrict: stores may alias weights -> no weight-load remat.
__global__ __launch_bounds__(512, 2) void k_xw(const float* __restrict__ hseq,
                                               const float* Wih,
                                               const float* __restrict__ bih,
                                               const float* __restrict__ bhh,
                                               float* xw){
    __shared__ float hs[32 * DIM];
    int g = threadIdx.x;
    int r0 = blockIdx.x * 32;
    {
        const float4* src = (const float4*)(hseq + (size_t)r0 * DIM);
        float4* dst = (float4*)hs;
        for (int j = g; j < 32 * 32; j += 512) dst[j] = src[j];
    }
    int gg = ((g & 3) << 7) + (g >> 2);
    const float4* wr = (const float4*)(Wih + (size_t)gg * DIM);
    W_DECL_ALL
    W_LOAD_ALL
    float bias = bih[gg] + bhh[gg];
    __syncthreads();
    for (int r = 0; r < 32; ++r){
        const float4* h4 = (const float4*)(hs + r * DIM);
        float a0 = bias, a1 = 0.f, a2 = 0.f, a3 = 0.f;
        DOT128(a0, a1, a2, a3)
        xw[(size_t)(r0 + r) * G4 + g] = (a0 + a1) + (a2 + a3);
    }
}

// ---------------- K3: LSTM scan, f16 dot2 + batched h flush ----------------
// 32 blocks x 512 threads. tid = cell*4 + kg. Thread holds Whh rows {q*128+cell},
// K-chunk [kg*32,+32) as 64 named half2 VGPRs; h transported in LDS as f16
// (4x b128/thread), fdot2 accumulates fp32. Butterfly shfl_xor(1,2) gives all
// 4 gate sums to the 4-lane group; redundant local activation + cell update.
// h output is staged in LDS (double-buffered) and flushed to global every 16
// steps right after a barrier -> the global-store drain at each step's barrier
// (the round-6 serial cost) is amortized to ~0.
__global__ __launch_bounds__(512, 2) void k_scan(const float* __restrict__ xw,
                                                 const float* Whh,
                                                 float* hseq){
    __shared__ _Float16 hsf[2][160];        // 4 chunks x (32 f16 + 8 pad), 80B stride
    __shared__ float stg[2][16][DIM];       // 16-step h staging, double-buffered (16 KB)
    const int tid = threadIdx.x;
    const int b = blockIdx.x;
    const int ci = tid >> 2;     // cell 0..127
    const int kg = tid & 3;      // K-chunk 0..3

    WDECLH(pA) WDECLH(pB) WDECLH(pC) WDECLH(pD)
    {
        const float4* s0 = (const float4*)(Whh + ((size_t)(0 * DIM + ci)) * DIM + kg * 32);
        const float4* s1 = (const float4*)(Whh + ((size_t)(1 * DIM + ci)) * DIM + kg * 32);
        const float4* s2 = (const float4*)(Whh + ((size_t)(2 * DIM + ci)) * DIM + kg * 32);
        const float4* s3 = (const float4*)(Whh + ((size_t)(3 * DIM + ci)) * DIM + kg * 32);
        WCVTH(pA, s0) WCVTH(pB, s1) WCVTH(pC, s2) WCVTH(pD, s3)
    }
    float c = 0.f;
    if (tid < 160) hsf[0][tid] = (_Float16)0.f;
    const float* xwb = xw + (size_t)b * SS * G4 + ci * 4;
    float* hout = hseq + (size_t)b * SS * DIM;
    float4 xr = *(const float4*)xwb;
    __syncthreads();
    int p = 0;
    for (int t = 0; t < SS; ++t){
        float4 xn = {0.f, 0.f, 0.f, 0.f};
        if (t + 1 < SS) xn = *(const float4*)(xwb + (size_t)(t + 1) * G4);   // prefetch (L2/L3)
        const uint4v* hc = (const uint4v*)(&hsf[p][kg * 40]);
        uint4v q0 = hc[0], q1 = hc[1], q2 = hc[2], q3 = hc[3];
        h2 d0 = B2H(q0.x), d1  = B2H(q0.y), d2  = B2H(q0.z), d3  = B2H(q0.w),
           d4 = B2H(q1.x), d5  = B2H(q1.y), d6  = B2H(q1.z), d7  = B2H(q1.w),
           d8 = B2H(q2.x), d9  = B2H(q2.y), d10 = B2H(q2.z), d11 = B2H(q2.w),
           d12= B2H(q3.x), d13 = B2H(q3.y), d14 = B2H(q3.z), d15 = B2H(q3.w);
        float a0 = 0.f, a1 = 0.f, a2 = 0.f, a3 = 0.f;
        DOTH(pA, a0) DOTH(pB, a1) DOTH(pC, a2) DOTH(pD, a3)
        a0 += __shfl_xor(a0, 1); a0 += __shfl_xor(a0, 2);
        a1 += __shfl_xor(a1, 1); a1 += __shfl_xor(a1, 2);
        a2 += __shfl_xor(a2, 1); a2 += __shfl_xor(a2, 2);
        a3 += __shfl_xor(a3, 1); a3 += __shfl_xor(a3, 2);
        float iv = sigm_(xr.x + a0);
        float fv = sigm_(xr.y + a1);
        float gv = tanh_(xr.z + a2);
        float ov = sigm_(xr.w + a3);
        c = fv * c + iv * gv;
        float h = ov * tanh_(c);
        if (kg == 0) hsf[p ^ 1][(ci >> 5) * 40 + (ci & 31)] = (_Float16)h;
        if (kg == 1) stg[(t >> 4) & 1][t & 15][ci] = h;
        __syncthreads();
        if ((t & 15) == 15){   // burst-flush 16 steps of h; drain hidden under next step
            int srow = tid >> 5, c4 = tid & 31;
            float4 v = *(const float4*)&stg[(t >> 4) & 1][srow][c4 * 4];
            *(float4*)(hout + (size_t)(t - 15 + srow) * DIM + c4 * 4) = v;
        }
        xr = xn; p ^= 1;
    }
}

// ---------------- K4: LayerNorm -> bf16 ----------------
__global__ void k_ln(const float* __restrict__ hseq, const float* __restrict__ gamma,
                     const float* __restrict__ beta, __hip_bfloat16* __restrict__ hn){
    int wid = threadIdx.x >> 6;
    int lane = threadIdx.x & 63;
    int row = blockIdx.x * 4 + wid;
    float2 hv = ((const float2*)(hseq + (size_t)row * DIM))[lane];
    float s = hv.x + hv.y;
    float sq = fmaf(hv.x, hv.x, hv.y * hv.y);
    for (int off = 32; off; off >>= 1){ s += __shfl_xor(s, off); sq += __shfl_xor(sq, off); }
    float mu = s * (1.f / 128.f);
    float var = sq * (1.f / 128.f) - mu * mu;
    float inv = rsqrtf(var + 1e-5f);
    float2 gv = ((const float2*)gamma)[lane];
    float2 bv = ((const float2*)beta)[lane];
    __hip_bfloat162 pr;
    pr.x = __float2bfloat16((hv.x - mu) * inv * gv.x + bv.x);
    pr.y = __float2bfloat16((hv.y - mu) * inv * gv.y + bv.y);
    ((__hip_bfloat162*)hn)[(size_t)row * 64 + lane] = pr;
}

// ---------------- K5: head_W fp32 -> bf16 ----------------
__global__ void k_cvt(const float* __restrict__ w, __hip_bfloat16* __restrict__ wb){
    int i = blockIdx.x * blockDim.x + threadIdx.x;
    float4 v = ((const float4*)w)[i];
    __hip_bfloat162 p0, p1;
    p0.x = __float2bfloat16(v.x); p0.y = __float2bfloat16(v.y);
    p1.x = __float2bfloat16(v.z); p1.y = __float2bfloat16(v.w);
    ((__hip_bfloat162*)wb)[2 * i]     = p0;
    ((__hip_bfloat162*)wb)[2 * i + 1] = p1;
}

// ---------------- K6: head GEMM (bf16 MFMA, swapped operands, nt float4 stores) -
__global__ __launch_bounds__(256) void k_head(const __hip_bfloat16* __restrict__ hn,
                                              const __hip_bfloat16* __restrict__ wb,
                                              const float* __restrict__ head_b,
                                              float* __restrict__ out){
    int bn = blockIdx.x;
    int bm = blockIdx.y;
    int wid = threadIdx.x >> 6;
    int lane = threadIdx.x & 63;
    int wr = wid >> 1, wc = wid & 1;
    int row0 = bm * 128 + wr * 64;
    int col0 = bn * 128 + wc * 64;
    const short* A  = (const short*)hn;   // [8192][128]
    const short* Bp = (const short*)wb;   // [32000][128]
    f32x4 zero = {0.f, 0.f, 0.f, 0.f};
    f32x4 acc[4][4];   // [mi][ni]
#pragma unroll
    for (int i = 0; i < 4; ++i)
#pragma unroll
        for (int j = 0; j < 4; ++j) acc[i][j] = zero;
    int lrow = lane & 15;
    int kgr = (lane >> 4) * 8;
#pragma unroll
    for (int ks = 0; ks < 4; ++ks){
        short8 a[4], bf[4];
#pragma unroll
        for (int mi = 0; mi < 4; ++mi)
            a[mi] = *(const short8*)(A + (size_t)(row0 + mi * 16 + lrow) * DIM + ks * 32 + kgr);
#pragma unroll
        for (int ni = 0; ni < 4; ++ni)
            bf[ni] = *(const short8*)(Bp + (size_t)(col0 + ni * 16 + lrow) * DIM + ks * 32 + kgr);
#pragma unroll
        for (int mi = 0; mi < 4; ++mi)
#pragma unroll
            for (int ni = 0; ni < 4; ++ni)
                acc[mi][ni] = __builtin_amdgcn_mfma_f32_16x16x32_bf16(bf[ni], a[mi], acc[mi][ni], 0, 0, 0);
    }
    int csub = (lane >> 4) * 4;
#pragma unroll
    for (int ni = 0; ni < 4; ++ni){
        int cbase = col0 + ni * 16 + csub;
        float4 b4 = ((const float4*)head_b)[cbase >> 2];
#pragma unroll
        for (int mi = 0; mi < 4; ++mi){
            int row = row0 + mi * 16 + lrow;
            f32x4 v;
            v[0] = acc[mi][ni][0] + b4.x;
            v[1] = acc[mi][ni][1] + b4.y;
            v[2] = acc[mi][ni][2] + b4.z;
            v[3] = acc[mi][ni][3] + b4.w;
            __builtin_nontemporal_store(v, (f32x4*)(out + (size_t)row * VOCAB + cbase));
        }
    }
}

extern "C" void kernel_launch(void* const* d_in, const int* in_sizes, int n_in,
                              void* d_out, int out_size, void* d_ws, size_t ws_size,
                              hipStream_t stream){
    const int*   x     = (const int*)  d_in[0];
    const float* emb   = (const float*)d_in[1];
    const float* Wih   = (const float*)d_in[2];
    const float* Whh   = (const float*)d_in[3];
    const float* bih   = (const float*)d_in[4];
    const float* bhh   = (const float*)d_in[5];
    const float* gamma = (const float*)d_in[6];
    const float* beta  = (const float*)d_in[7];
    const float* headW = (const float*)d_in[8];
    const float* headb = (const float*)d_in[9];
    float* out = (float*)d_out;

    char* ws = (char*)d_ws;
    float* xw   = (float*)ws;                                  // 16 MB [8192][512] (cell-major)
    float* hseq = (float*)(ws + (16u << 20));                  // 4 MB  [8192][128]
    __hip_bfloat16* hn = (__hip_bfloat16*)(ws + (20u << 20));  // 2 MB
    __hip_bfloat16* wb = (__hip_bfloat16*)(ws + (22u << 20));  // 8 MB

    k_embed<<<1024, 256, 0, stream>>>(x, emb, hseq);
    k_cvt  <<<4000, 256, 0, stream>>>(headW, wb);
    for (int l = 0; l < NL; ++l){
        k_xw  <<<256, 512, 0, stream>>>(hseq, Wih + (size_t)l * G4 * DIM,
                                        bih + l * G4, bhh + l * G4, xw);
        k_scan<<<32, 512, 0, stream>>>(xw, Whh + (size_t)l * G4 * DIM, hseq);
    }
    k_ln   <<<2048, 256, 0, stream>>>(hseq, gamma, beta, hn);
    k_head <<<dim3(250, 64), 256, 0, stream>>>(hn, wb, headb, out);
}

// Round 8
// 1319.787 us; speedup vs baseline: 1.1176x; 1.0597x over previous
//
#include <hip/hip_runtime.h>
#include <hip/hip_bf16.h>

#define DIM 128
#define G4 512      // 4*DIM
#define NL 4
#define VOCAB 32000
#define BB 32
#define SS 256
#define ROWS (BB*SS)   // 8192

typedef __attribute__((ext_vector_type(8))) short short8;
typedef __attribute__((ext_vector_type(4))) float f32x4;
typedef __attribute__((ext_vector_type(4))) unsigned int uint4v;
typedef __attribute__((ext_vector_type(2))) _Float16 h2;

__device__ __forceinline__ float fexp_(float x){ return __builtin_amdgcn_exp2f(x * 1.44269504088896f); }
__device__ __forceinline__ float frcp_(float x){ return __builtin_amdgcn_rcpf(x); }
__device__ __forceinline__ float sigm_(float x){ return frcp_(1.f + fexp_(-x)); }
__device__ __forceinline__ float tanh_(float x){
    float ax = fabsf(x);
    float e = fexp_(-2.f * ax);
    float t = (1.f - e) * frcp_(1.f + e);
    return x < 0.f ? -t : t;
}
__device__ __forceinline__ h2 mkh(float a, float b){ h2 r; r.x = (_Float16)a; r.y = (_Float16)b; return r; }

#if __has_builtin(__builtin_amdgcn_fdot2)
#define FDOT2(w, d, acc) acc = __builtin_amdgcn_fdot2(w, d, acc, false);
#else
#define FDOT2(w, d, acc) acc = fmaf((float)(w).x, (float)(d).x, fmaf((float)(w).y, (float)(d).y, acc));
#endif
#define B2H(u) __builtin_bit_cast(h2, (unsigned)(u))

// ---- per-gate 32-elem f16 weight block: 16 named half2 regs ----
#define WDECLH(p) h2 p##0,p##1,p##2,p##3,p##4,p##5,p##6,p##7, \
                     p##8,p##9,p##10,p##11,p##12,p##13,p##14,p##15;
#define WCVTH(p, src) { float4 t_; \
    t_=(src)[0]; p##0 =mkh(t_.x,t_.y); p##1 =mkh(t_.z,t_.w); \
    t_=(src)[1]; p##2 =mkh(t_.x,t_.y); p##3 =mkh(t_.z,t_.w); \
    t_=(src)[2]; p##4 =mkh(t_.x,t_.y); p##5 =mkh(t_.z,t_.w); \
    t_=(src)[3]; p##6 =mkh(t_.x,t_.y); p##7 =mkh(t_.z,t_.w); \
    t_=(src)[4]; p##8 =mkh(t_.x,t_.y); p##9 =mkh(t_.z,t_.w); \
    t_=(src)[5]; p##10=mkh(t_.x,t_.y); p##11=mkh(t_.z,t_.w); \
    t_=(src)[6]; p##12=mkh(t_.x,t_.y); p##13=mkh(t_.z,t_.w); \
    t_=(src)[7]; p##14=mkh(t_.x,t_.y); p##15=mkh(t_.z,t_.w); }
#define DOTH(p, acc) \
    FDOT2(p##0,d0,acc)  FDOT2(p##1,d1,acc)  FDOT2(p##2,d2,acc)  FDOT2(p##3,d3,acc) \
    FDOT2(p##4,d4,acc)  FDOT2(p##5,d5,acc)  FDOT2(p##6,d6,acc)  FDOT2(p##7,d7,acc) \
    FDOT2(p##8,d8,acc)  FDOT2(p##9,d9,acc)  FDOT2(p##10,d10,acc) FDOT2(p##11,d11,acc) \
    FDOT2(p##12,d12,acc) FDOT2(p##13,d13,acc) FDOT2(p##14,d14,acc) FDOT2(p##15,d15,acc)

// full-K (128) fp32 macros for k_xw (1 gate/thread, broadcast h)
#define W_DECL_ALL \
    float4 w0,w1,w2,w3,w4,w5,w6,w7,w8,w9,w10,w11,w12,w13,w14,w15, \
           w16,w17,w18,w19,w20,w21,w22,w23,w24,w25,w26,w27,w28,w29,w30,w31;
#define W_LOAD(i) w##i = wr[i];
#define W_LOAD_ALL \
    W_LOAD(0) W_LOAD(1) W_LOAD(2) W_LOAD(3) W_LOAD(4) W_LOAD(5) W_LOAD(6) W_LOAD(7) \
    W_LOAD(8) W_LOAD(9) W_LOAD(10) W_LOAD(11) W_LOAD(12) W_LOAD(13) W_LOAD(14) W_LOAD(15) \
    W_LOAD(16) W_LOAD(17) W_LOAD(18) W_LOAD(19) W_LOAD(20) W_LOAD(21) W_LOAD(22) W_LOAD(23) \
    W_LOAD(24) W_LOAD(25) W_LOAD(26) W_LOAD(27) W_LOAD(28) W_LOAD(29) W_LOAD(30) W_LOAD(31)
#define FMA1(i, acc) acc = fmaf(h4[i].x, w##i.x, fmaf(h4[i].y, w##i.y, \
                      fmaf(h4[i].z, w##i.z, fmaf(h4[i].w, w##i.w, acc))));
#define DOT128(a0,a1,a2,a3) \
    FMA1(0,a0) FMA1(1,a0) FMA1(2,a0) FMA1(3,a0) FMA1(4,a0) FMA1(5,a0) FMA1(6,a0) FMA1(7,a0) \
    FMA1(8,a1) FMA1(9,a1) FMA1(10,a1) FMA1(11,a1) FMA1(12,a1) FMA1(13,a1) FMA1(14,a1) FMA1(15,a1) \
    FMA1(16,a2) FMA1(17,a2) FMA1(18,a2) FMA1(19,a2) FMA1(20,a2) FMA1(21,a2) FMA1(22,a2) FMA1(23,a2) \
    FMA1(24,a3) FMA1(25,a3) FMA1(26,a3) FMA1(27,a3) FMA1(28,a3) FMA1(29,a3) FMA1(30,a3) FMA1(31,a3)

// ---------------- K1: embedding gather ----------------
__global__ void k_embed(const int* __restrict__ x, const float* __restrict__ emb,
                        float* __restrict__ hseq){
    int i = blockIdx.x * blockDim.x + threadIdx.x;
    int row = i >> 5;
    int d4  = i & 31;
    int tok = x[row];
    ((float4*)hseq)[i] = ((const float4*)emb)[tok * 32 + d4];
}

// ---------------- K2: xw = hseq @ Wih^T + bih + bhh (cell-major layout) --------
// Thread tid owns gate gg = (tid&3)*128 + (tid>>2); store index == tid, so
// stores coalesce AND k_scan reads one float4 (i,f,g,o) per cell.
// Wih/xw NON-restrict: stores may alias weights -> no weight-load remat.
__global__ __launch_bounds__(512, 2) void k_xw(const float* __restrict__ hseq,
                                               const float* Wih,
                                               const float* __restrict__ bih,
                                               const float* __restrict__ bhh,
                                               float* xw){
    __shared__ float hs[32 * DIM];
    int g = threadIdx.x;
    int r0 = blockIdx.x * 32;
    {
        const float4* src = (const float4*)(hseq + (size_t)r0 * DIM);
        float4* dst = (float4*)hs;
        for (int j = g; j < 32 * 32; j += 512) dst[j] = src[j];
    }
    int gg = ((g & 3) << 7) + (g >> 2);
    const float4* wr = (const float4*)(Wih + (size_t)gg * DIM);
    W_DECL_ALL
    W_LOAD_ALL
    float bias = bih[gg] + bhh[gg];
    __syncthreads();
    for (int r = 0; r < 32; ++r){
        const float4* h4 = (const float4*)(hs + r * DIM);
        float a0 = bias, a1 = 0.f, a2 = 0.f, a3 = 0.f;
        DOT128(a0, a1, a2, a3)
        xw[(size_t)(r0 + r) * G4 + g] = (a0 + a1) + (a2 + a3);
    }
}

// ---------------- K3: LSTM scan, f16 dot2 + register-chunked xw ----------------
// 32 blocks x 512 threads. tid = cell*4 + kg. Thread holds Whh rows {q*128+cell},
// K-chunk [kg*32,+32) as 64 named half2 VGPRs.
// KEY CHANGE (round 8): the per-step global xw load is gone. The scan runs in
// 16 chunks of 16 unrolled steps; at each chunk top the thread loads its gate
// quad for the next 16 steps into 16 NAMED float4 regs (statically indexed by
// the unroll), and the previous chunk's h tile is flushed to global. All
// global ops drain at the chunk's FIRST barrier (one ~900cyc stall / 16 steps);
// the inner 15 steps have no global ops, so their vmcnt(0)-before-barrier
// drains nothing (the round-7 per-step exposed-load cost).
__global__ __launch_bounds__(512, 2) void k_scan(const float* __restrict__ xw,
                                                 const float* Whh,
                                                 float* hseq){
    __shared__ _Float16 hsf[2][160];        // 4 chunks x (32 f16 + 8 pad), 80B stride
    __shared__ float stg[2][16][DIM];       // 16-step h staging, double-buffered (16 KB)
    const int tid = threadIdx.x;
    const int b = blockIdx.x;
    const int ci = tid >> 2;     // cell 0..127
    const int kg = tid & 3;      // K-chunk 0..3

    WDECLH(pA) WDECLH(pB) WDECLH(pC) WDECLH(pD)
    {
        const float4* s0 = (const float4*)(Whh + ((size_t)(0 * DIM + ci)) * DIM + kg * 32);
        const float4* s1 = (const float4*)(Whh + ((size_t)(1 * DIM + ci)) * DIM + kg * 32);
        const float4* s2 = (const float4*)(Whh + ((size_t)(2 * DIM + ci)) * DIM + kg * 32);
        const float4* s3 = (const float4*)(Whh + ((size_t)(3 * DIM + ci)) * DIM + kg * 32);
        WCVTH(pA, s0) WCVTH(pB, s1) WCVTH(pC, s2) WCVTH(pD, s3)
    }
    float c = 0.f;
    if (tid < 160) hsf[0][tid] = (_Float16)0.f;
    const float4* xb = (const float4*)(xw + (size_t)b * SS * G4);   // [256][128] float4
    float* hout = hseq + (size_t)b * SS * DIM;
    const int srow = tid >> 5, c4 = tid & 31;   // flush coords
    __syncthreads();
    int p = 0;

#define SCAN_STEP(XQ, CH, I) { \
        const uint4v* hc = (const uint4v*)(&hsf[p][kg * 40]); \
        uint4v q0 = hc[0], q1 = hc[1], q2 = hc[2], q3 = hc[3]; \
        h2 d0 = B2H(q0.x), d1  = B2H(q0.y), d2  = B2H(q0.z), d3  = B2H(q0.w), \
           d4 = B2H(q1.x), d5  = B2H(q1.y), d6  = B2H(q1.z), d7  = B2H(q1.w), \
           d8 = B2H(q2.x), d9  = B2H(q2.y), d10 = B2H(q2.z), d11 = B2H(q2.w), \
           d12= B2H(q3.x), d13 = B2H(q3.y), d14 = B2H(q3.z), d15 = B2H(q3.w); \
        float a0 = 0.f, a1 = 0.f, a2 = 0.f, a3 = 0.f; \
        DOTH(pA, a0) DOTH(pB, a1) DOTH(pC, a2) DOTH(pD, a3) \
        a0 += __shfl_xor(a0, 1); a0 += __shfl_xor(a0, 2); \
        a1 += __shfl_xor(a1, 1); a1 += __shfl_xor(a1, 2); \
        a2 += __shfl_xor(a2, 1); a2 += __shfl_xor(a2, 2); \
        a3 += __shfl_xor(a3, 1); a3 += __shfl_xor(a3, 2); \
        float iv = sigm_(XQ.x + a0); \
        float fv = sigm_(XQ.y + a1); \
        float gv = tanh_(XQ.z + a2); \
        float ov = sigm_(XQ.w + a3); \
        c = fv * c + iv * gv; \
        float h = ov * tanh_(c); \
        if (kg == 0) hsf[p ^ 1][(ci >> 5) * 40 + (ci & 31)] = (_Float16)h; \
        if (kg == 1) stg[(CH) & 1][I][ci] = h; \
        __syncthreads(); \
        p ^= 1; }

    for (int ch = 0; ch < 16; ++ch){
        if (ch > 0){   // flush previous chunk's h tile (drains at first barrier below)
            float4 v = *(const float4*)&stg[(ch - 1) & 1][srow][c4 * 4];
            *(float4*)(hout + (size_t)((ch - 1) * 16 + srow) * DIM + c4 * 4) = v;
        }
        const int t0 = ch * 16;
        // 16 coalesced quad loads into NAMED regs (consumed by static unroll)
        float4 xq0  = xb[(t0 +  0) * 128 + ci], xq1  = xb[(t0 +  1) * 128 + ci],
               xq2  = xb[(t0 +  2) * 128 + ci], xq3  = xb[(t0 +  3) * 128 + ci],
               xq4  = xb[(t0 +  4) * 128 + ci], xq5  = xb[(t0 +  5) * 128 + ci],
               xq6  = xb[(t0 +  6) * 128 + ci], xq7  = xb[(t0 +  7) * 128 + ci],
               xq8  = xb[(t0 +  8) * 128 + ci], xq9  = xb[(t0 +  9) * 128 + ci],
               xq10 = xb[(t0 + 10) * 128 + ci], xq11 = xb[(t0 + 11) * 128 + ci],
               xq12 = xb[(t0 + 12) * 128 + ci], xq13 = xb[(t0 + 13) * 128 + ci],
               xq14 = xb[(t0 + 14) * 128 + ci], xq15 = xb[(t0 + 15) * 128 + ci];
        SCAN_STEP(xq0,  ch, 0)  SCAN_STEP(xq1,  ch, 1)  SCAN_STEP(xq2,  ch, 2)  SCAN_STEP(xq3,  ch, 3)
        SCAN_STEP(xq4,  ch, 4)  SCAN_STEP(xq5,  ch, 5)  SCAN_STEP(xq6,  ch, 6)  SCAN_STEP(xq7,  ch, 7)
        SCAN_STEP(xq8,  ch, 8)  SCAN_STEP(xq9,  ch, 9)  SCAN_STEP(xq10, ch, 10) SCAN_STEP(xq11, ch, 11)
        SCAN_STEP(xq12, ch, 12) SCAN_STEP(xq13, ch, 13) SCAN_STEP(xq14, ch, 14) SCAN_STEP(xq15, ch, 15)
    }
    {   // final flush (chunk 15 -> stg buffer 1)
        float4 v = *(const float4*)&stg[1][srow][c4 * 4];
        *(float4*)(hout + (size_t)(240 + srow) * DIM + c4 * 4) = v;
    }
#undef SCAN_STEP
}

// ---------------- K4: LayerNorm -> bf16 ----------------
__global__ void k_ln(const float* __restrict__ hseq, const float* __restrict__ gamma,
                     const float* __restrict__ beta, __hip_bfloat16* __restrict__ hn){
    int wid = threadIdx.x >> 6;
    int lane = threadIdx.x & 63;
    int row = blockIdx.x * 4 + wid;
    float2 hv = ((const float2*)(hseq + (size_t)row * DIM))[lane];
    float s = hv.x + hv.y;
    float sq = fmaf(hv.x, hv.x, hv.y * hv.y);
    for (int off = 32; off; off >>= 1){ s += __shfl_xor(s, off); sq += __shfl_xor(sq, off); }
    float mu = s * (1.f / 128.f);
    float var = sq * (1.f / 128.f) - mu * mu;
    float inv = rsqrtf(var + 1e-5f);
    float2 gv = ((const float2*)gamma)[lane];
    float2 bv = ((const float2*)beta)[lane];
    __hip_bfloat162 pr;
    pr.x = __float2bfloat16((hv.x - mu) * inv * gv.x + bv.x);
    pr.y = __float2bfloat16((hv.y - mu) * inv * gv.y + bv.y);
    ((__hip_bfloat162*)hn)[(size_t)row * 64 + lane] = pr;
}

// ---------------- K5: head_W fp32 -> bf16 ----------------
__global__ void k_cvt(const float* __restrict__ w, __hip_bfloat16* __restrict__ wb){
    int i = blockIdx.x * blockDim.x + threadIdx.x;
    float4 v = ((const float4*)w)[i];
    __hip_bfloat162 p0, p1;
    p0.x = __float2bfloat16(v.x); p0.y = __float2bfloat16(v.y);
    p1.x = __float2bfloat16(v.z); p1.y = __float2bfloat16(v.w);
    ((__hip_bfloat162*)wb)[2 * i]     = p0;
    ((__hip_bfloat162*)wb)[2 * i + 1] = p1;
}

// ---------------- K6: head GEMM (bf16 MFMA, swapped operands, nt float4 stores) -
__global__ __launch_bounds__(256) void k_head(const __hip_bfloat16* __restrict__ hn,
                                              const __hip_bfloat16* __restrict__ wb,
                                              const float* __restrict__ head_b,
                                              float* __restrict__ out){
    int bn = blockIdx.x;
    int bm = blockIdx.y;
    int wid = threadIdx.x >> 6;
    int lane = threadIdx.x & 63;
    int wr = wid >> 1, wc = wid & 1;
    int row0 = bm * 128 + wr * 64;
    int col0 = bn * 128 + wc * 64;
    const short* A  = (const short*)hn;   // [8192][128]
    const short* Bp = (const short*)wb;   // [32000][128]
    f32x4 zero = {0.f, 0.f, 0.f, 0.f};
    f32x4 acc[4][4];   // [mi][ni]
#pragma unroll
    for (int i = 0; i < 4; ++i)
#pragma unroll
        for (int j = 0; j < 4; ++j) acc[i][j] = zero;
    int lrow = lane & 15;
    int kgr = (lane >> 4) * 8;
#pragma unroll
    for (int ks = 0; ks < 4; ++ks){
        short8 a[4], bf[4];
#pragma unroll
        for (int mi = 0; mi < 4; ++mi)
            a[mi] = *(const short8*)(A + (size_t)(row0 + mi * 16 + lrow) * DIM + ks * 32 + kgr);
#pragma unroll
        for (int ni = 0; ni < 4; ++ni)
            bf[ni] = *(const short8*)(Bp + (size_t)(col0 + ni * 16 + lrow) * DIM + ks * 32 + kgr);
#pragma unroll
        for (int mi = 0; mi < 4; ++mi)
#pragma unroll
            for (int ni = 0; ni < 4; ++ni)
                acc[mi][ni] = __builtin_amdgcn_mfma_f32_16x16x32_bf16(bf[ni], a[mi], acc[mi][ni], 0, 0, 0);
    }
    int csub = (lane >> 4) * 4;
#pragma unroll
    for (int ni = 0; ni < 4; ++ni){
        int cbase = col0 + ni * 16 + csub;
        float4 b4 = ((const float4*)head_b)[cbase >> 2];
#pragma unroll
        for (int mi = 0; mi < 4; ++mi){
            int row = row0 + mi * 16 + lrow;
            f32x4 v;
            v[0] = acc[mi][ni][0] + b4.x;
            v[1] = acc[mi][ni][1] + b4.y;
            v[2] = acc[mi][ni][2] + b4.z;
            v[3] = acc[mi][ni][3] + b4.w;
            __builtin_nontemporal_store(v, (f32x4*)(out + (size_t)row * VOCAB + cbase));
        }
    }
}

extern "C" void kernel_launch(void* const* d_in, const int* in_sizes, int n_in,
                              void* d_out, int out_size, void* d_ws, size_t ws_size,
                              hipStream_t stream){
    const int*   x     = (const int*)  d_in[0];
    const float* emb   = (const float*)d_in[1];
    const float* Wih   = (const float*)d_in[2];
    const float* Whh   = (const float*)d_in[3];
    const float* bih   = (const float*)d_in[4];
    const float* bhh   = (const float*)d_in[5];
    const float* gamma = (const float*)d_in[6];
    const float* beta  = (const float*)d_in[7];
    const float* headW = (const float*)d_in[8];
    const float* headb = (const float*)d_in[9];
    float* out = (float*)d_out;

    char* ws = (char*)d_ws;
    float* xw   = (float*)ws;                                  // 16 MB [8192][512] (cell-major)
    float* hseq = (float*)(ws + (16u << 20));                  // 4 MB  [8192][128]
    __hip_bfloat16* hn = (__hip_bfloat16*)(ws + (20u << 20));  // 2 MB
    __hip_bfloat16* wb = (__hip_bfloat16*)(ws + (22u << 20));  // 8 MB

    k_embed<<<1024, 256, 0, stream>>>(x, emb, hseq);
    k_cvt  <<<4000, 256, 0, stream>>>(headW, wb);
    for (int l = 0; l < NL; ++l){
        k_xw  <<<256, 512, 0, stream>>>(hseq, Wih + (size_t)l * G4 * DIM,
                                        bih + l * G4, bhh + l * G4, xw);
        k_scan<<<32, 512, 0, stream>>>(xw, Whh + (size_t)l * G4 * DIM, hseq);
    }
    k_ln   <<<2048, 256, 0, stream>>>(hseq, gamma, beta, hn);
    k_head <<<dim3(250, 64), 256, 0, stream>>>(hn, wb, headb, out);
}

// Round 9
// 1265.509 us; speedup vs baseline: 1.1655x; 1.0429x over previous
//
#include <hip/hip_runtime.h>
#include <hip/hip_bf16.h>

#define DIM 128
#define G4 512      // 4*DIM
#define NL 4
#define VOCAB 32000
#define BB 32
#define SS 256
#define ROWS (BB*SS)   // 8192

typedef __attribute__((ext_vector_type(8))) short short8;
typedef __attribute__((ext_vector_type(4))) float f32x4;
typedef __attribute__((ext_vector_type(4))) unsigned int uint4v;
typedef __attribute__((ext_vector_type(2))) _Float16 h2;

__device__ __forceinline__ float fexp_(float x){ return __builtin_amdgcn_exp2f(x * 1.44269504088896f); }
__device__ __forceinline__ float frcp_(float x){ return __builtin_amdgcn_rcpf(x); }
__device__ __forceinline__ float sigm_(float x){ return frcp_(1.f + fexp_(-x)); }
__device__ __forceinline__ float tanh_(float x){
    float ax = fabsf(x);
    float e = fexp_(-2.f * ax);
    float t = (1.f - e) * frcp_(1.f + e);
    return x < 0.f ? -t : t;
}
__device__ __forceinline__ h2 mkh(float a, float b){ h2 r; r.x = (_Float16)a; r.y = (_Float16)b; return r; }

#if __has_builtin(__builtin_amdgcn_fdot2)
#define FDOT2(w, d, acc) acc = __builtin_amdgcn_fdot2(w, d, acc, false);
#else
#define FDOT2(w, d, acc) acc = fmaf((float)(w).x, (float)(d).x, fmaf((float)(w).y, (float)(d).y, acc));
#endif
#define B2H(u) __builtin_bit_cast(h2, (unsigned)(u))

// ---- 32 named half2 regs per gate (64 weights, K-chunk 64) ----
#define WD32(p) h2 p##0,p##1,p##2,p##3,p##4,p##5,p##6,p##7,p##8,p##9,p##10,p##11, \
                   p##12,p##13,p##14,p##15,p##16,p##17,p##18,p##19,p##20,p##21,p##22,p##23, \
                   p##24,p##25,p##26,p##27,p##28,p##29,p##30,p##31;
#define WCVT32(p, src) { float4 t_; \
    t_=(src)[0];  p##0 =mkh(t_.x,t_.y); p##1 =mkh(t_.z,t_.w); \
    t_=(src)[1];  p##2 =mkh(t_.x,t_.y); p##3 =mkh(t_.z,t_.w); \
    t_=(src)[2];  p##4 =mkh(t_.x,t_.y); p##5 =mkh(t_.z,t_.w); \
    t_=(src)[3];  p##6 =mkh(t_.x,t_.y); p##7 =mkh(t_.z,t_.w); \
    t_=(src)[4];  p##8 =mkh(t_.x,t_.y); p##9 =mkh(t_.z,t_.w); \
    t_=(src)[5];  p##10=mkh(t_.x,t_.y); p##11=mkh(t_.z,t_.w); \
    t_=(src)[6];  p##12=mkh(t_.x,t_.y); p##13=mkh(t_.z,t_.w); \
    t_=(src)[7];  p##14=mkh(t_.x,t_.y); p##15=mkh(t_.z,t_.w); \
    t_=(src)[8];  p##16=mkh(t_.x,t_.y); p##17=mkh(t_.z,t_.w); \
    t_=(src)[9];  p##18=mkh(t_.x,t_.y); p##19=mkh(t_.z,t_.w); \
    t_=(src)[10]; p##20=mkh(t_.x,t_.y); p##21=mkh(t_.z,t_.w); \
    t_=(src)[11]; p##22=mkh(t_.x,t_.y); p##23=mkh(t_.z,t_.w); \
    t_=(src)[12]; p##24=mkh(t_.x,t_.y); p##25=mkh(t_.z,t_.w); \
    t_=(src)[13]; p##26=mkh(t_.x,t_.y); p##27=mkh(t_.z,t_.w); \
    t_=(src)[14]; p##28=mkh(t_.x,t_.y); p##29=mkh(t_.z,t_.w); \
    t_=(src)[15]; p##30=mkh(t_.x,t_.y); p##31=mkh(t_.z,t_.w); }
#define DT_LO(p, acc) \
    FDOT2(p##0,d0,acc)  FDOT2(p##1,d1,acc)  FDOT2(p##2,d2,acc)  FDOT2(p##3,d3,acc) \
    FDOT2(p##4,d4,acc)  FDOT2(p##5,d5,acc)  FDOT2(p##6,d6,acc)  FDOT2(p##7,d7,acc) \
    FDOT2(p##8,d8,acc)  FDOT2(p##9,d9,acc)  FDOT2(p##10,d10,acc) FDOT2(p##11,d11,acc) \
    FDOT2(p##12,d12,acc) FDOT2(p##13,d13,acc) FDOT2(p##14,d14,acc) FDOT2(p##15,d15,acc)
#define DT_HI(p, acc) \
    FDOT2(p##16,d0,acc)  FDOT2(p##17,d1,acc)  FDOT2(p##18,d2,acc)  FDOT2(p##19,d3,acc) \
    FDOT2(p##20,d4,acc)  FDOT2(p##21,d5,acc)  FDOT2(p##22,d6,acc)  FDOT2(p##23,d7,acc) \
    FDOT2(p##24,d8,acc)  FDOT2(p##25,d9,acc)  FDOT2(p##26,d10,acc) FDOT2(p##27,d11,acc) \
    FDOT2(p##28,d12,acc) FDOT2(p##29,d13,acc) FDOT2(p##30,d14,acc) FDOT2(p##31,d15,acc)
#define RD16(base) { const uint4v* hc_ = (const uint4v*)(base); \
    uint4v q0_=hc_[0], q1_=hc_[1], q2_=hc_[2], q3_=hc_[3]; \
    d0=B2H(q0_.x); d1=B2H(q0_.y); d2=B2H(q0_.z); d3=B2H(q0_.w); \
    d4=B2H(q1_.x); d5=B2H(q1_.y); d6=B2H(q1_.z); d7=B2H(q1_.w); \
    d8=B2H(q2_.x); d9=B2H(q2_.y); d10=B2H(q2_.z); d11=B2H(q2_.w); \
    d12=B2H(q3_.x); d13=B2H(q3_.y); d14=B2H(q3_.z); d15=B2H(q3_.w); }

// full-K (128) fp32 macros for k_xw (1 gate/thread, broadcast h)
#define W_DECL_ALL \
    float4 w0,w1,w2,w3,w4,w5,w6,w7,w8,w9,w10,w11,w12,w13,w14,w15, \
           w16,w17,w18,w19,w20,w21,w22,w23,w24,w25,w26,w27,w28,w29,w30,w31;
#define W_LOAD(i) w##i = wr[i];
#define W_LOAD_ALL \
    W_LOAD(0) W_LOAD(1) W_LOAD(2) W_LOAD(3) W_LOAD(4) W_LOAD(5) W_LOAD(6) W_LOAD(7) \
    W_LOAD(8) W_LOAD(9) W_LOAD(10) W_LOAD(11) W_LOAD(12) W_LOAD(13) W_LOAD(14) W_LOAD(15) \
    W_LOAD(16) W_LOAD(17) W_LOAD(18) W_LOAD(19) W_LOAD(20) W_LOAD(21) W_LOAD(22) W_LOAD(23) \
    W_LOAD(24) W_LOAD(25) W_LOAD(26) W_LOAD(27) W_LOAD(28) W_LOAD(29) W_LOAD(30) W_LOAD(31)
#define FMA1(i, acc) acc = fmaf(h4[i].x, w##i.x, fmaf(h4[i].y, w##i.y, \
                      fmaf(h4[i].z, w##i.z, fmaf(h4[i].w, w##i.w, acc))));
#define DOT128(a0,a1,a2,a3) \
    FMA1(0,a0) FMA1(1,a0) FMA1(2,a0) FMA1(3,a0) FMA1(4,a0) FMA1(5,a0) FMA1(6,a0) FMA1(7,a0) \
    FMA1(8,a1) FMA1(9,a1) FMA1(10,a1) FMA1(11,a1) FMA1(12,a1) FMA1(13,a1) FMA1(14,a1) FMA1(15,a1) \
    FMA1(16,a2) FMA1(17,a2) FMA1(18,a2) FMA1(19,a2) FMA1(20,a2) FMA1(21,a2) FMA1(22,a2) FMA1(23,a2) \
    FMA1(24,a3) FMA1(25,a3) FMA1(26,a3) FMA1(27,a3) FMA1(28,a3) FMA1(29,a3) FMA1(30,a3) FMA1(31,a3)

// ---------------- K1: embedding gather ----------------
__global__ void k_embed(const int* __restrict__ x, const float* __restrict__ emb,
                        float* __restrict__ hseq){
    int i = blockIdx.x * blockDim.x + threadIdx.x;
    int row = i >> 5;
    int d4  = i & 31;
    int tok = x[row];
    ((float4*)hseq)[i] = ((const float4*)emb)[tok * 32 + d4];
}

// ---------------- K2: xw = hseq @ Wih^T + bih + bhh (cell-major layout) --------
__global__ __launch_bounds__(512, 2) void k_xw(const float* __restrict__ hseq,
                                               const float* Wih,
                                               const float* __restrict__ bih,
                                               const float* __restrict__ bhh,
                                               float* xw){
    __shared__ float hs[32 * DIM];
    int g = threadIdx.x;
    int r0 = blockIdx.x * 32;
    {
        const float4* src = (const float4*)(hseq + (size_t)r0 * DIM);
        float4* dst = (float4*)hs;
        for (int j = g; j < 32 * 32; j += 512) dst[j] = src[j];
    }
    int gg = ((g & 3) << 7) + (g >> 2);
    const float4* wr = (const float4*)(Wih + (size_t)gg * DIM);
    W_DECL_ALL
    W_LOAD_ALL
    float bias = bih[gg] + bhh[gg];
    __syncthreads();
    for (int r = 0; r < 32; ++r){
        const float4* h4 = (const float4*)(hs + r * DIM);
        float a0 = bias, a1 = 0.f, a2 = 0.f, a3 = 0.f;
        DOT128(a0, a1, a2, a3)
        xw[(size_t)(r0 + r) * G4 + g] = (a0 + a1) + (a2 + a3);
    }
}

// ---------------- K3: fused 2-layer LSTM scan (in-block pipeline) ----------------
// 32 blocks (one per batch) x 768 threads (12 waves, 3/SIMD).
// quarter 0 (tid 0..255)  : layer A recurrence (xw_A from k_xw via LDS chunks)
// quarter 1 (tid 256..511): layer B recurrence (lag 2), xw_B from xwbuf
// quarter 2 (tid 512..767): computes Wih_B @ h_A (lag 1) -> xwbuf (+bias)
// Each thread: (ci, kg) with K-chunk 64; 128 half2 weight VGPRs (unified names
// across quarters -> no multiplied liveness); fdot2 in 2 passes of 32 halves.
// Single barrier per step; h rings in LDS (%4); h_B flushed to global per 16 steps.
__global__ __launch_bounds__(768, 3) void k_scan2(
    const float* __restrict__ xw,
    const float* WhhA, const float* WihB, const float* WhhB,
    const float* __restrict__ bihB, const float* __restrict__ bhhB,
    float* hseqOut)
{
    __shared__ float    xwstage[2][16][512];   // 64 KB  xw_A chunks
    __shared__ float    stg[2][16][128];       // 16 KB  h_B staging
    __shared__ float4   xwbuf[2][128];         //  4 KB  B-in -> B-rec handoff
    __shared__ _Float16 hA[4][144];            // h_A ring
    __shared__ _Float16 hB[4][144];            // h_B ring

    const int tid = threadIdx.x;
    const int b = blockIdx.x;
    const int quarter = tid >> 8;        // 0=A, 1=B-rec, 2=B-in
    const int qt = tid & 255;
    const int ci = qt >> 1, kg = qt & 1;

    const float* Wsel = (quarter == 0) ? WhhA : (quarter == 1) ? WhhB : WihB;
    WD32(pi) WD32(pf) WD32(pg) WD32(po)
    {
        const float4* s0 = (const float4*)(Wsel + ((size_t)(0 * DIM + ci)) * DIM + kg * 64);
        const float4* s1 = (const float4*)(Wsel + ((size_t)(1 * DIM + ci)) * DIM + kg * 64);
        const float4* s2 = (const float4*)(Wsel + ((size_t)(2 * DIM + ci)) * DIM + kg * 64);
        const float4* s3 = (const float4*)(Wsel + ((size_t)(3 * DIM + ci)) * DIM + kg * 64);
        WCVT32(pi, s0) WCVT32(pf, s1) WCVT32(pg, s2) WCVT32(po, s3)
    }
    float4 biasv = {0.f, 0.f, 0.f, 0.f};
    if (quarter == 2){   // bias folded into xwbuf by B-in (keeps B-rec chain short)
        biasv.x = bihB[0 * DIM + ci] + bhhB[0 * DIM + ci];
        biasv.y = bihB[1 * DIM + ci] + bhhB[1 * DIM + ci];
        biasv.z = bihB[2 * DIM + ci] + bhhB[2 * DIM + ci];
        biasv.w = bihB[3 * DIM + ci] + bhhB[3 * DIM + ci];
    }
    if (tid < 576){ ((_Float16*)hA)[tid] = (_Float16)0.f; ((_Float16*)hB)[tid] = (_Float16)0.f; }
    const float4* xw4 = (const float4*)(xw + (size_t)b * SS * G4);
    {   // stage chunk 0
        float4* dst = (float4*)&xwstage[0][0][0];
#pragma unroll
        for (int j = 0; j < 3; ++j){ int idx = j * 768 + tid; if (idx < 2048) dst[idx] = xw4[idx]; }
    }
    float cc = 0.f;
    float* hout = hseqOut + (size_t)b * SS * DIM;
    __syncthreads();

    for (int s = 0; s < 258; ++s){
        // flush completed h_B group (group g done at s=16g+17; flush at s=16g+18)
        if (s >= 18 && ((s - 2) & 15) == 0 && tid < 512){
            int g = ((s - 2) >> 4) - 1;
            int r = tid >> 5, c4 = tid & 31;
            float4 v = *(const float4*)&stg[g & 1][r][c4 * 4];
            *(float4*)(hout + (size_t)(g * 16 + r) * DIM + c4 * 4) = v;
        }
        // prefetch next xw_A chunk into the other buffer
        if ((s & 15) == 0 && s < 240){
            int c1 = (s >> 4) + 1;
            const float4* src = xw4 + c1 * 2048;
            float4* dst = (float4*)&xwstage[c1 & 1][0][0];
#pragma unroll
            for (int j = 0; j < 3; ++j){ int idx = j * 768 + tid; if (idx < 2048) dst[idx] = src[idx]; }
        }
        bool act;
        const _Float16* rb;
        if (quarter == 0){      act = (s < 256);            rb = &hA[(s - 1) & 3][kg * 64]; }
        else if (quarter == 1){ act = (s >= 2);             rb = &hB[(s - 3) & 3][kg * 64]; }
        else {                  act = (s >= 1 && s < 257);  rb = &hA[(s - 1) & 3][kg * 64]; }
        if (act){
            h2 d0,d1,d2,d3,d4,d5,d6,d7,d8,d9,d10,d11,d12,d13,d14,d15;
            float a0 = 0.f, a1 = 0.f, a2 = 0.f, a3 = 0.f;
            RD16(rb)
            DT_LO(pi, a0) DT_LO(pf, a1) DT_LO(pg, a2) DT_LO(po, a3)
            RD16(rb + 32)
            DT_HI(pi, a0) DT_HI(pf, a1) DT_HI(pg, a2) DT_HI(po, a3)
            a0 += __shfl_xor(a0, 1); a1 += __shfl_xor(a1, 1);
            a2 += __shfl_xor(a2, 1); a3 += __shfl_xor(a3, 1);
            if (quarter == 2){
                if (kg == 0){
                    float4 v; v.x = a0 + biasv.x; v.y = a1 + biasv.y;
                              v.z = a2 + biasv.z; v.w = a3 + biasv.w;
                    xwbuf[s & 1][ci] = v;
                }
            } else {
                float4 xq;
                if (quarter == 0) xq = *(const float4*)&xwstage[(s >> 4) & 1][s & 15][ci * 4];
                else              xq = xwbuf[(s - 1) & 1][ci];
                float iv = sigm_(xq.x + a0);
                float fv = sigm_(xq.y + a1);
                float gv = tanh_(xq.z + a2);
                float ov = sigm_(xq.w + a3);
                cc = fv * cc + iv * gv;
                float h = ov * tanh_(cc);
                if (quarter == 0){
                    if (kg == 0) hA[s & 3][ci] = (_Float16)h;
                } else {
                    int u = s - 2;
                    if (kg == 0) hB[u & 3][ci] = (_Float16)h;
                    else         stg[(u >> 4) & 1][u & 15][ci] = h;
                }
            }
        }
        __syncthreads();
    }
    // final flush: group 15 (rows 240..255), staged in stg[1]
    if (tid < 512){
        int r = tid >> 5, c4 = tid & 31;
        float4 v = *(const float4*)&stg[1][r][c4 * 4];
        *(float4*)(hout + (size_t)(240 + r) * DIM + c4 * 4) = v;
    }
}

// ---------------- K4: LayerNorm -> bf16 ----------------
__global__ void k_ln(const float* __restrict__ hseq, const float* __restrict__ gamma,
                     const float* __restrict__ beta, __hip_bfloat16* __restrict__ hn){
    int wid = threadIdx.x >> 6;
    int lane = threadIdx.x & 63;
    int row = blockIdx.x * 4 + wid;
    float2 hv = ((const float2*)(hseq + (size_t)row * DIM))[lane];
    float s = hv.x + hv.y;
    float sq = fmaf(hv.x, hv.x, hv.y * hv.y);
    for (int off = 32; off; off >>= 1){ s += __shfl_xor(s, off); sq += __shfl_xor(sq, off); }
    float mu = s * (1.f / 128.f);
    float var = sq * (1.f / 128.f) - mu * mu;
    float inv = rsqrtf(var + 1e-5f);
    float2 gv = ((const float2*)gamma)[lane];
    float2 bv = ((const float2*)beta)[lane];
    __hip_bfloat162 pr;
    pr.x = __float2bfloat16((hv.x - mu) * inv * gv.x + bv.x);
    pr.y = __float2bfloat16((hv.y - mu) * inv * gv.y + bv.y);
    ((__hip_bfloat162*)hn)[(size_t)row * 64 + lane] = pr;
}

// ---------------- K5: head_W fp32 -> bf16 ----------------
__global__ void k_cvt(const float* __restrict__ w, __hip_bfloat16* __restrict__ wb){
    int i = blockIdx.x * blockDim.x + threadIdx.x;
    float4 v = ((const float4*)w)[i];
    __hip_bfloat162 p0, p1;
    p0.x = __float2bfloat16(v.x); p0.y = __float2bfloat16(v.y);
    p1.x = __float2bfloat16(v.z); p1.y = __float2bfloat16(v.w);
    ((__hip_bfloat162*)wb)[2 * i]     = p0;
    ((__hip_bfloat162*)wb)[2 * i + 1] = p1;
}

// ---------------- K6: head GEMM (bf16 MFMA, swapped operands, nt float4 stores) -
__global__ __launch_bounds__(256) void k_head(const __hip_bfloat16* __restrict__ hn,
                                              const __hip_bfloat16* __restrict__ wb,
                                              const float* __restrict__ head_b,
                                              float* __restrict__ out){
    int bn = blockIdx.x;
    int bm = blockIdx.y;
    int wid = threadIdx.x >> 6;
    int lane = threadIdx.x & 63;
    int wr = wid >> 1, wc = wid & 1;
    int row0 = bm * 128 + wr * 64;
    int col0 = bn * 128 + wc * 64;
    const short* A  = (const short*)hn;   // [8192][128]
    const short* Bp = (const short*)wb;   // [32000][128]
    f32x4 zero = {0.f, 0.f, 0.f, 0.f};
    f32x4 acc[4][4];
#pragma unroll
    for (int i = 0; i < 4; ++i)
#pragma unroll
        for (int j = 0; j < 4; ++j) acc[i][j] = zero;
    int lrow = lane & 15;
    int kgr = (lane >> 4) * 8;
#pragma unroll
    for (int ks = 0; ks < 4; ++ks){
        short8 a[4], bf[4];
#pragma unroll
        for (int mi = 0; mi < 4; ++mi)
            a[mi] = *(const short8*)(A + (size_t)(row0 + mi * 16 + lrow) * DIM + ks * 32 + kgr);
#pragma unroll
        for (int ni = 0; ni < 4; ++ni)
            bf[ni] = *(const short8*)(Bp + (size_t)(col0 + ni * 16 + lrow) * DIM + ks * 32 + kgr);
#pragma unroll
        for (int mi = 0; mi < 4; ++mi)
#pragma unroll
            for (int ni = 0; ni < 4; ++ni)
                acc[mi][ni] = __builtin_amdgcn_mfma_f32_16x16x32_bf16(bf[ni], a[mi], acc[mi][ni], 0, 0, 0);
    }
    int csub = (lane >> 4) * 4;
#pragma unroll
    for (int ni = 0; ni < 4; ++ni){
        int cbase = col0 + ni * 16 + csub;
        float4 b4 = ((const float4*)head_b)[cbase >> 2];
#pragma unroll
        for (int mi = 0; mi < 4; ++mi){
            int row = row0 + mi * 16 + lrow;
            f32x4 v;
            v[0] = acc[mi][ni][0] + b4.x;
            v[1] = acc[mi][ni][1] + b4.y;
            v[2] = acc[mi][ni][2] + b4.z;
            v[3] = acc[mi][ni][3] + b4.w;
            __builtin_nontemporal_store(v, (f32x4*)(out + (size_t)row * VOCAB + cbase));
        }
    }
}

extern "C" void kernel_launch(void* const* d_in, const int* in_sizes, int n_in,
                              void* d_out, int out_size, void* d_ws, size_t ws_size,
                              hipStream_t stream){
    const int*   x     = (const int*)  d_in[0];
    const float* emb   = (const float*)d_in[1];
    const float* Wih   = (const float*)d_in[2];
    const float* Whh   = (const float*)d_in[3];
    const float* bih   = (const float*)d_in[4];
    const float* bhh   = (const float*)d_in[5];
    const float* gamma = (const float*)d_in[6];
    const float* beta  = (const float*)d_in[7];
    const float* headW = (const float*)d_in[8];
    const float* headb = (const float*)d_in[9];
    float* out = (float*)d_out;

    char* ws = (char*)d_ws;
    float* xw   = (float*)ws;                                  // 16 MB [8192][512] (cell-major)
    float* hseq = (float*)(ws + (16u << 20));                  // 4 MB  [8192][128]
    __hip_bfloat16* hn = (__hip_bfloat16*)(ws + (20u << 20));  // 2 MB
    __hip_bfloat16* wb = (__hip_bfloat16*)(ws + (22u << 20));  // 8 MB

    const size_t WSZ = (size_t)G4 * DIM;   // 65536 floats per layer weight matrix

    k_embed<<<1024, 256, 0, stream>>>(x, emb, hseq);
    k_cvt  <<<4000, 256, 0, stream>>>(headW, wb);
    // layers 0+1 fused
    k_xw   <<<256, 512, 0, stream>>>(hseq, Wih, bih, bhh, xw);
    k_scan2<<<32, 768, 0, stream>>>(xw, Whh, Wih + WSZ, Whh + WSZ,
                                    bih + G4, bhh + G4, hseq);
    // layers 2+3 fused
    k_xw   <<<256, 512, 0, stream>>>(hseq, Wih + 2 * WSZ, bih + 2 * G4, bhh + 2 * G4, xw);
    k_scan2<<<32, 768, 0, stream>>>(xw, Whh + 2 * WSZ, Wih + 3 * WSZ, Whh + 3 * WSZ,
                                    bih + 3 * G4, bhh + 3 * G4, hseq);
    k_ln   <<<2048, 256, 0, stream>>>(hseq, gamma, beta, hn);
    k_head <<<dim3(250, 64), 256, 0, stream>>>(hn, wb, headb, out);
}